// Round 16
// baseline (67.578 us; speedup 1.0000x reference)
//
#include <hip/hip_runtime.h>
#include <hip/hip_bf16.h>
#include <stdint.h>

// TarMAC ensemble attention, MI355X/gfx950.
// E=128 ensembles x NB=256 agents, DQ=DK=DV=256 (D=768), f32 in/out, bf16 MFMA compute.
//
// R16 = R10 + in-kernel K staging (R8's mechanism) ; prep = Vt only.
// Model revision: warm path is TRAFFIC-bound (~300MB logical vs 256MB L3;
// five ILP variants R11/R13/R15 all null). Largest reducible bytes = Kb
// round-trip (32MB). R8-vs-R9 isolated that in-kernel K-cvt was neutral(+2us)
// vs the round-trip at equal aud; R8's regression was the ballot-aud alone.
// So: K staged f32->bf16 in-kernel (ISSUE loads early / cvt+ds_write late,
// regs live only across one MFMA burst), stagger-aud + everything else R10.
//
// Workspace (16 MiB): Vt @ 0 (per-e transposed V bf16).

#define EE   128
#define NBB  256
#define DDIM 768
#define NEGV (-1000000.0f)

typedef __attribute__((ext_vector_type(8))) short short8;   // 8 x bf16 (4 VGPRs)
typedef __attribute__((ext_vector_type(4))) float f32x4;    // MFMA accumulator

__device__ __forceinline__ unsigned short f2bf(float f){
  union { float f; unsigned u; } v; v.f = f;
  return (unsigned short)((v.u + 0x7FFFu + ((v.u >> 16) & 1u)) >> 16);  // RNE, finite inputs
}
// RNE cast the compiler fuses into v_cvt_pk_bf16_f32 (m240: don't hand-write asm)
__device__ __forceinline__ unsigned short cvt1(float f){
  __hip_bfloat16 h = __float2bfloat16(f);
  unsigned short u; __builtin_memcpy(&u, &h, 2); return u;
}
__device__ __forceinline__ unsigned pk2(float lo, float hi){
  return (unsigned)cvt1(lo) | ((unsigned)cvt1(hi) << 16);
}

// Row-swaps across the 4 16-lane groups (rows) of a wave.
__device__ __forceinline__ void swap32(unsigned &a, unsigned &b){
#if __has_builtin(__builtin_amdgcn_permlane32_swap)
  auto r = __builtin_amdgcn_permlane32_swap(a, b, false, false);
  a = r[0]; b = r[1];
#else
  const int up = threadIdx.x & 32;
  const unsigned ax = __shfl_xor(a, 32), bx = __shfl_xor(b, 32);
  const unsigned na = up ? bx : a, nb = up ? b : ax;
  a = na; b = nb;
#endif
}
__device__ __forceinline__ void swap16(unsigned &a, unsigned &b){
#if __has_builtin(__builtin_amdgcn_permlane16_swap)
  auto r = __builtin_amdgcn_permlane16_swap(a, b, false, false);
  a = r[0]; b = r[1];
#else
  const int odd = threadIdx.x & 16;
  const unsigned ax = __shfl_xor(a, 16), bx = __shfl_xor(b, 16);
  const unsigned na = odd ? bx : a, nb = odd ? b : ax;
  a = na; b = nb;
#endif
}

// async global->LDS, 16B per lane; LDS dest = wave-uniform base + lane*16 (HW rule)
__device__ __forceinline__ void gload16(const void* g, void* l){
  __builtin_amdgcn_global_load_lds((const __attribute__((address_space(1))) unsigned*)g,
                                   (__attribute__((address_space(3))) unsigned*)l, 16, 0, 0);
}
// Stage 64 bf16 rows (this wave: rows wave*16..+16) with read-side XOR swizzle
// folded into the per-lane GLOBAL column (LDS dest linear, m173 pattern).
__device__ __forceinline__ void gstage(const unsigned short* __restrict__ base,
                                       unsigned short* __restrict__ buf,
                                       int wave, int lane){
  #pragma unroll
  for(int i = 0; i < 8; ++i){
    const int lrow = wave*16 + i*2 + (lane >> 5);
    const int col  = ((lane & 31) * 8) ^ ((lrow & 7) << 3);
    gload16(base + (size_t)lrow * 256 + col, buf + (wave*16 + i*2) * 256);
  }
}

// ---------- kernel 1: V + noise -> transposed bf16 (Vt[e][d][k]) ----------
__global__ void k_prep_vt(const float* __restrict__ qkv, const float* __restrict__ noise,
                          unsigned short* __restrict__ Vt){
  __shared__ unsigned short tile[64 * 66];     // 64x64 tile, stride 66 to spread banks
  const int b = blockIdx.x;
  const int e = b >> 4, t4 = b & 15;
  const int k0 = (t4 >> 2) << 6, d0 = (t4 & 3) << 6;
  const int u = threadIdx.x & 15, r = threadIdx.x >> 4;
  #pragma unroll
  for(int i = 0; i < 4; ++i){
    const int kl = r + (i << 4);
    const size_t off = ((size_t)(e*NBB + k0 + kl)) * DDIM + 512 + d0 + (u << 2);
    f32x4 v  = *(const f32x4*)(qkv   + off);
    f32x4 nz = *(const f32x4*)(noise + off);
    const int base = kl * 66 + (u << 2);
    tile[base+0] = f2bf(v[0]+nz[0]); tile[base+1] = f2bf(v[1]+nz[1]);
    tile[base+2] = f2bf(v[2]+nz[2]); tile[base+3] = f2bf(v[3]+nz[3]);
  }
  __syncthreads();
  #pragma unroll
  for(int i = 0; i < 4; ++i){
    const int dl = r + (i << 4);
    unsigned short o0 = tile[(u*4+0)*66 + dl];
    unsigned short o1 = tile[(u*4+1)*66 + dl];
    unsigned short o2 = tile[(u*4+2)*66 + dl];
    unsigned short o3 = tile[(u*4+3)*66 + dl];
    *(ushort4*)(Vt + ((size_t)(e*NBB + d0 + dl)) * NBB + k0 + (u << 2)) =
        make_ushort4(o0, o1, o2, o3);
  }
}

// ---------- kernel 2: fused attention ----------
// Block = (e, q-quarter): 4 waves x 16 q-rows each. 16x16x32 bf16 MFMA, swapped
// QK^T (S^T = mfma(K,Q)) -> lane-local softmax + in-register P via permlane.
// K staged f32->bf16 in-kernel (no Kb workspace); V from Vt via gload_lds.
// LDS 68KB: buf0/buf1 (2x32KB tiles, read-XOR-swizzled), aud 2KB, pos 2KB.
__launch_bounds__(256, 2)
__global__ void k_attn(const float* __restrict__ qkv, const float* __restrict__ noise,
                       const float* __restrict__ sp,
                       const unsigned char* __restrict__ m8, const int* __restrict__ m32,
                       const float* __restrict__ pos,
                       const unsigned short* __restrict__ Vt,
                       float* __restrict__ out){
  extern __shared__ unsigned char smem[];
  unsigned short* buf0 = (unsigned short*)smem;             // 64 x 256 bf16
  unsigned short* buf1 = (unsigned short*)(smem + 32768);   // 64 x 256 bf16
  unsigned*       audL = (unsigned*)(smem + 65536);         // 64 rows x 8 words
  float*          posx = (float*)(smem + 67584);            // 256
  float*          posy = (float*)(smem + 68608);            // 256

  // bid = x + 8*qq + 32*c ; e = 16x + c  -> the 4 q-quarters of an ensemble all
  // land on XCD x (bid%8) -> K f32 re-read x4 and Vt reuse stay in that L2.
  const int bid = blockIdx.x;
  const int e   = ((bid & 7) << 4) + (bid >> 5);
  const int qq  = (bid >> 3) & 3;
  const int tid  = threadIdx.x;
  const int wave = tid >> 6;
  const int lane = tid & 63;
  const int g    = lane >> 4;
  const int u    = lane & 15;
  const int q0   = qq * 64 + wave * 16;        // first q-row of this wave
  const size_t ebase = (size_t)e * NBB;

  // K staging registers: 8 groups x (2 f32x4 qkv + 2 f32x4 noise) = one 64-row
  // tile per block-iteration. Live range: ISSUE -> next WRITE (one MFMA burst).
  f32x4 ka[8], kb4[8], na4[8], nb4[8];
  #define K_ISSUE(kq)                                                          \
    _Pragma("unroll")                                                          \
    for(int i = 0; i < 8; ++i){                                                \
      const int row = wave*16 + i*2 + (lane >> 5);                             \
      const size_t goff = (ebase + (kq)*64 + row) * DDIM + 256 + (lane & 31)*8;\
      ka[i]  = *(const f32x4*)(qkv + goff);                                    \
      kb4[i] = *(const f32x4*)(qkv + goff + 4);                                \
      na4[i] = *(const f32x4*)(noise + goff);                                  \
      nb4[i] = *(const f32x4*)(noise + goff + 4);                              \
    }
  #define K_WRITE(buf)                                                         \
    _Pragma("unroll")                                                          \
    for(int i = 0; i < 8; ++i){                                                \
      const int row = wave*16 + i*2 + (lane >> 5);                             \
      short8 o;                                                                \
      o[0]=cvt1(ka[i][0]+na4[i][0]); o[1]=cvt1(ka[i][1]+na4[i][1]);            \
      o[2]=cvt1(ka[i][2]+na4[i][2]); o[3]=cvt1(ka[i][3]+na4[i][3]);            \
      o[4]=cvt1(kb4[i][0]+nb4[i][0]); o[5]=cvt1(kb4[i][1]+nb4[i][1]);          \
      o[6]=cvt1(kb4[i][2]+nb4[i][2]); o[7]=cvt1(kb4[i][3]+nb4[i][3]);          \
      const int col = ((lane & 31)*8) ^ ((row & 7) << 3);                      \
      *(short8*)((buf) + row*256 + col) = o;                                   \
    }

  // ---- phase 0: positions ----
  {
    const float2 p = *(const float2*)(pos + (ebase + tid) * 2);
    posx[tid] = p.x; posy[tid] = p.y;
  }
  const unsigned probe = ((const unsigned*)m32)[tid & 63];
  const int isInt = !__any(probe > 1u);        // wave-uniform dtype probe
  __syncthreads();                             // pos ready

  // ---- phase 0b: audible bits (R10 staggered, bank-conflict-free; no staging
  // regs live here) ----
  #pragma unroll
  for(int h = 0; h < 2; ++h){
    const int w   = tid + h * 256;             // word index within block [0,512)
    const int row = w >> 3;                    // q-row within block [0,64)
    const int j   = w & 7;                     // which 32-key word
    const float qx = posx[qq*64 + row], qy = posy[qq*64 + row];
    const size_t mbase = (ebase + qq*64 + row) * NBB + j * 32;
    unsigned wd = 0u;
    if(isInt){
      #pragma unroll
      for(int ii = 0; ii < 8; ++ii){
        const int blk = (ii + j) & 7;          // stagger by word index
        const int4 mv = *(const int4*)(m32 + mbase + blk * 4);
        const int mvals[4] = {mv.x, mv.y, mv.z, mv.w};
        #pragma unroll
        for(int jj = 0; jj < 4; ++jj){
          const int kk = blk * 4 + jj;
          const int k  = j * 32 + kk;
          const float dx = posx[k] - qx, dy = posy[k] - qy;
          // block fp-contract so sqrt boundary matches numpy exactly
          const float d2 = __fadd_rn(__fmul_rn(dx, dx), __fmul_rn(dy, dy));
          if((mvals[jj] != 0) && (sqrtf(d2) < 15.0f)) wd |= 1u << kk;
        }
      }
    } else {
      #pragma unroll
      for(int i = 0; i < 2; ++i){
        const int4 mv = *(const int4*)(m8 + mbase + i * 16);   // 16 bool bytes
        const int mvals[4] = {mv.x, mv.y, mv.z, mv.w};
        #pragma unroll
        for(int jt = 0; jt < 4; ++jt){
          const int jj = (jt + j) & 3;         // stagger byte-groups -> 2-way (free)
          #pragma unroll
          for(int b = 0; b < 4; ++b){
            const int kk = i * 16 + jj * 4 + b;
            const int k  = j * 32 + kk;
            const float dx = posx[k] - qx, dy = posy[k] - qy;
            const float d2 = __fadd_rn(__fmul_rn(dx, dx), __fmul_rn(dy, dy));
            if((((unsigned)mvals[jj] >> (8 * b)) & 0xFFu) && (sqrtf(d2) < 15.0f)) wd |= 1u << kk;
          }
        }
      }
    }
    audL[w] = wd;
  }

  K_ISSUE(0);                                  // K tile 0 loads lead the VMEM queue

  // ---- phase 1: Q fragments from f32 global (scale + RNE cvt); K0 in flight --
  const float scale = fabsf(sp[0]) + 1.0f;
  short8 qf[8];
  {
    const float* qrow = qkv + (ebase + q0 + u) * DDIM;
    #pragma unroll
    for(int dk = 0; dk < 8; ++dk){
      f32x4 a = *(const f32x4*)(qrow + dk*32 + g*8);
      f32x4 b = *(const f32x4*)(qrow + dk*32 + g*8 + 4);
      short8 f;
      f[0]=cvt1(a[0]*scale); f[1]=cvt1(a[1]*scale); f[2]=cvt1(a[2]*scale); f[3]=cvt1(a[3]*scale);
      f[4]=cvt1(b[0]*scale); f[5]=cvt1(b[1]*scale); f[6]=cvt1(b[2]*scale); f[7]=cvt1(b[3]*scale);
      qf[dk] = f;
    }
  }

  const f32x4 zero4 = {0.f, 0.f, 0.f, 0.f};
  f32x4 acc[16];
  #pragma unroll
  for(int nt = 0; nt < 16; ++nt) acc[nt] = zero4;

  // ---- phase 2: S^T = K Q^T, double-buffered; K cvt'd in-kernel (R8 loop) ----
  // per tile: [cvt+write kq] [issue loads kq+1] [barrier] [MFMA kq]
  // write(kq)->buf[kq&1] is safe: its last readers (MFMA kq-2) precede
  // barrier(kq-1) in every wave's program order.   acc[nt] at lane (g,u):
  // S[k = nt*16 + g*4 + r][q = u]
  #pragma unroll
  for(int kq = 0; kq < 4; ++kq){
    unsigned short* cur = (kq & 1) ? buf1 : buf0;
    K_WRITE(cur);
    if(kq < 3) K_ISSUE(kq + 1);
    __syncthreads();
    if(kq == 3) gstage(Vt + ebase * 256, buf0, wave, lane);  // V0 under MFMA+softmax
    #pragma unroll
    for(int nth = 0; nth < 4; ++nth){
      const unsigned short* kr = cur + (nth*16 + u) * 256;
      const int sw = (u & 7) << 3;
      #pragma unroll
      for(int dk = 0; dk < 8; ++dk){
        short8 kb = *(const short8*)(kr + ((dk*32 + g*8) ^ sw));
        acc[kq*4 + nth] = __builtin_amdgcn_mfma_f32_16x16x32_bf16(kb, qf[dk], acc[kq*4 + nth], 0, 0, 0);
      }
    }
  }

  // ---- phase 3: mask + softmax, lane-local rows + 2 shfl reduces ----
  unsigned wmask[8];
  {
    const unsigned* arow = audL + (wave*16 + u) * 8;   // own wave's rows
    #pragma unroll
    for(int j = 0; j < 8; ++j) wmask[j] = arow[j];
  }
  const unsigned anyw = wmask[0]|wmask[1]|wmask[2]|wmask[3]|wmask[4]|wmask[5]|wmask[6]|wmask[7];
  const unsigned long long rowsAny = __ballot(anyw != 0u);   // bit u = row u has keys

  float m0=-3.0e38f, m1=-3.0e38f, m2=-3.0e38f, m3=-3.0e38f;
  #pragma unroll
  for(int nt = 0; nt < 16; ++nt){
    const unsigned wv = wmask[nt >> 1] >> (((nt & 1) << 4) + g*4);
    f32x4 s = acc[nt];
    s[0] = s[0]*0.0625f + ((wv      & 1u) ? 0.0f : NEGV);  // /sqrt(256) + mask bias
    s[1] = s[1]*0.0625f + (((wv>>1) & 1u) ? 0.0f : NEGV);
    s[2] = s[2]*0.0625f + (((wv>>2) & 1u) ? 0.0f : NEGV);
    s[3] = s[3]*0.0625f + (((wv>>3) & 1u) ? 0.0f : NEGV);
    acc[nt] = s;
    m0 = fmaxf(m0, s[0]); m1 = fmaxf(m1, s[1]);
    m2 = fmaxf(m2, s[2]); m3 = fmaxf(m3, s[3]);
  }
  float mx = fmaxf(fmaxf(m0, m1), fmaxf(m2, m3));
  mx = fmaxf(mx, __shfl_xor(mx, 16));
  mx = fmaxf(mx, __shfl_xor(mx, 32));
  float s0=0.f, s1=0.f, s2=0.f, s3=0.f;
  #pragma unroll
  for(int nt = 0; nt < 16; ++nt){
    f32x4 p = acc[nt];
    p[0] = __expf(p[0] - mx); p[1] = __expf(p[1] - mx);
    p[2] = __expf(p[2] - mx); p[3] = __expf(p[3] - mx);
    acc[nt] = p;
    s0 += p[0]; s1 += p[1]; s2 += p[2]; s3 += p[3];
  }
  float ssum = (s0 + s1) + (s2 + s3);
  ssum += __shfl_xor(ssum, 16);
  ssum += __shfl_xor(ssum, 32);
  const float inv = 1.0f / ssum;               // ssum >= 1 always (max element)

  // ---- phase 3b: P -> bf16 in-register + permlane relayout to PV A-frags ----
  short8 pa[8];
  #pragma unroll
  for(int kt = 0; kt < 8; ++kt){
    unsigned cE = pk2(acc[2*kt][0]*inv,   acc[2*kt][1]*inv);
    unsigned dE = pk2(acc[2*kt][2]*inv,   acc[2*kt][3]*inv);
    unsigned cO = pk2(acc[2*kt+1][0]*inv, acc[2*kt+1][1]*inv);
    unsigned dO = pk2(acc[2*kt+1][2]*inv, acc[2*kt+1][3]*inv);
    swap32(cE, cO); swap16(cE, cO);
    swap32(dE, dO); swap16(dE, dO);
    union { short8 s; unsigned w[4]; } pk;
    pk.w[0] = cE; pk.w[1] = dE; pk.w[2] = cO; pk.w[3] = dO;
    pa[kt] = pk.s;
  }

  __syncthreads();                             // drains V0 gloads; all waves past QKT

  // ---- phase 4: x = P V, gload_lds double-buffered pipeline over Vt quarters ----
  #pragma unroll
  for(int dqt = 0; dqt < 4; ++dqt){
    unsigned short* cur = (dqt & 1) ? buf1 : buf0;
    unsigned short* nxt = (dqt & 1) ? buf0 : buf1;
    if(dqt < 3) gstage(Vt + (ebase + (size_t)(dqt+1) * 64) * 256, nxt, wave, lane);
    f32x4 xacc[4];
    #pragma unroll
    for(int dt = 0; dt < 4; ++dt) xacc[dt] = zero4;
    #pragma unroll
    for(int dt = 0; dt < 4; ++dt){
      const unsigned short* vr = cur + (dt*16 + u) * 256;
      const int sw = (u & 7) << 3;
      #pragma unroll
      for(int kt = 0; kt < 8; ++kt){
        short8 bv = *(const short8*)(vr + ((kt*32 + g*8) ^ sw));
        xacc[dt] = __builtin_amdgcn_mfma_f32_16x16x32_bf16(pa[kt], bv, xacc[dt], 0, 0, 0);
      }
    }
    #pragma unroll
    for(int r = 0; r < 4; ++r){
      const float zf = ((rowsAny >> (g*4 + r)) & 1ull) ? 1.0f : 0.0f;
      float* orow = out + (ebase + q0 + g*4 + r) * 256 + dqt*64;
      #pragma unroll
      for(int dt = 0; dt < 4; ++dt)
        orow[dt*16 + u] = xacc[dt][r] * zf;    // rows with no audible key -> 0
    }
    if(dqt < 3) __syncthreads();
  }
}

extern "C" void kernel_launch(void* const* d_in, const int* in_sizes, int n_in,
                              void* d_out, int out_size, void* d_ws, size_t ws_size,
                              hipStream_t stream){
  (void)in_sizes; (void)n_in; (void)out_size; (void)ws_size;  // needs 16 MB ws
  const float* qkv   = (const float*)d_in[0];
  const void*  mask  = d_in[1];
  const float* pos   = (const float*)d_in[2];
  const float* noise = (const float*)d_in[3];
  const float* sp    = (const float*)d_in[4];

  unsigned short* Vt = (unsigned short*)d_ws;
  float* outp = (float*)d_out;

  k_prep_vt<<<2048, 256, 0, stream>>>(qkv, noise, Vt);

  hipFuncSetAttribute((const void*)k_attn, hipFuncAttributeMaxDynamicSharedMemorySize, 69632);
  k_attn<<<512, 256, 69632, stream>>>(qkv, noise, sp,
                                      (const unsigned char*)mask, (const int*)mask,
                                      pos, Vt, outp);
}

// Round 17
// 65.752 us; speedup vs baseline: 1.0278x; 1.0278x over previous
//
#include <hip/hip_runtime.h>
#include <hip/hip_bf16.h>
#include <stdint.h>

// TarMAC ensemble attention, MI355X/gfx950.
// E=128 ensembles x NB=256 agents, DQ=DK=DV=256 (D=768), f32 in/out, bf16 MFMA compute.
//
// R17 = R10 VERBATIM — the measured optimum (65.8us). Plateau evidence:
// R7=66.0 (same structure, pre-stagger-aud), R13=66.4 (+setprio, null),
// R15=66.65 (counted-vmcnt 3-buf pipeline, null), R16=67.6 (Kb round-trip
// removed via in-kernel K-cvt, null-negative), R11/R12/R14 = regressions
// (aud-in-loop scheduling break; prep divergence; no-LDS 8x L2 traffic).
// Warm path is mixed L3/HBM traffic-bound (~300MB logical at ~4.6TB/s
// effective); schedule- and traffic-level levers are exhausted at this
// (e, q-quarter) x 4-wave decomposition.
//
// Workspace (32 MiB): Vt @ 0 (16 MiB), Kb @ 16 MiB (32768x256 bf16).

#define EE   128
#define NBB  256
#define DDIM 768
#define NEGV (-1000000.0f)

typedef __attribute__((ext_vector_type(8))) short short8;   // 8 x bf16 (4 VGPRs)
typedef __attribute__((ext_vector_type(4))) float f32x4;    // MFMA accumulator

__device__ __forceinline__ unsigned short f2bf(float f){
  union { float f; unsigned u; } v; v.f = f;
  return (unsigned short)((v.u + 0x7FFFu + ((v.u >> 16) & 1u)) >> 16);  // RNE, finite inputs
}
// RNE cast the compiler fuses into v_cvt_pk_bf16_f32 (m240: don't hand-write asm)
__device__ __forceinline__ unsigned short cvt1(float f){
  __hip_bfloat16 h = __float2bfloat16(f);
  unsigned short u; __builtin_memcpy(&u, &h, 2); return u;
}
__device__ __forceinline__ unsigned pk2(float lo, float hi){
  return (unsigned)cvt1(lo) | ((unsigned)cvt1(hi) << 16);
}

// Row-swaps across the 4 16-lane groups (rows) of a wave.
__device__ __forceinline__ void swap32(unsigned &a, unsigned &b){
#if __has_builtin(__builtin_amdgcn_permlane32_swap)
  auto r = __builtin_amdgcn_permlane32_swap(a, b, false, false);
  a = r[0]; b = r[1];
#else
  const int up = threadIdx.x & 32;
  const unsigned ax = __shfl_xor(a, 32), bx = __shfl_xor(b, 32);
  const unsigned na = up ? bx : a, nb = up ? b : ax;
  a = na; b = nb;
#endif
}
__device__ __forceinline__ void swap16(unsigned &a, unsigned &b){
#if __has_builtin(__builtin_amdgcn_permlane16_swap)
  auto r = __builtin_amdgcn_permlane16_swap(a, b, false, false);
  a = r[0]; b = r[1];
#else
  const int odd = threadIdx.x & 16;
  const unsigned ax = __shfl_xor(a, 16), bx = __shfl_xor(b, 16);
  const unsigned na = odd ? bx : a, nb = odd ? b : ax;
  a = na; b = nb;
#endif
}

// async global->LDS, 16B per lane; LDS dest = wave-uniform base + lane*16 (HW rule)
__device__ __forceinline__ void gload16(const void* g, void* l){
  __builtin_amdgcn_global_load_lds((const __attribute__((address_space(1))) unsigned*)g,
                                   (__attribute__((address_space(3))) unsigned*)l, 16, 0, 0);
}
// Stage 64 bf16 rows (this wave: rows wave*16..+16) with read-side XOR swizzle
// folded into the per-lane GLOBAL column (LDS dest linear, m173 pattern).
__device__ __forceinline__ void gstage(const unsigned short* __restrict__ base,
                                       unsigned short* __restrict__ buf,
                                       int wave, int lane){
  #pragma unroll
  for(int i = 0; i < 8; ++i){
    const int lrow = wave*16 + i*2 + (lane >> 5);
    const int col  = ((lane & 31) * 8) ^ ((lrow & 7) << 3);
    gload16(base + (size_t)lrow * 256 + col, buf + (wave*16 + i*2) * 256);
  }
}

// ---------- kernel 1: prep ----------
// blocks [0,2048): V + noise -> transposed Vt[e][d][k] bf16.
// blocks [2048,6144): K + noise -> Kb[n][d] bf16 rows (streaming convert).
__global__ void k_prep(const float* __restrict__ qkv, const float* __restrict__ noise,
                       unsigned short* __restrict__ Vt, unsigned short* __restrict__ Kb){
  __shared__ unsigned short tile[64 * 66];
  if(blockIdx.x < 2048){
    const int b = blockIdx.x;
    const int e = b >> 4, t4 = b & 15;
    const int k0 = (t4 >> 2) << 6, d0 = (t4 & 3) << 6;
    const int u = threadIdx.x & 15, r = threadIdx.x >> 4;
    #pragma unroll
    for(int i = 0; i < 4; ++i){
      const int kl = r + (i << 4);
      const size_t off = ((size_t)(e*NBB + k0 + kl)) * DDIM + 512 + d0 + (u << 2);
      f32x4 v  = *(const f32x4*)(qkv   + off);
      f32x4 nz = *(const f32x4*)(noise + off);
      const int base = kl * 66 + (u << 2);
      tile[base+0] = f2bf(v[0]+nz[0]); tile[base+1] = f2bf(v[1]+nz[1]);
      tile[base+2] = f2bf(v[2]+nz[2]); tile[base+3] = f2bf(v[3]+nz[3]);
    }
    __syncthreads();
    #pragma unroll
    for(int i = 0; i < 4; ++i){
      const int dl = r + (i << 4);
      unsigned short o0 = tile[(u*4+0)*66 + dl];
      unsigned short o1 = tile[(u*4+1)*66 + dl];
      unsigned short o2 = tile[(u*4+2)*66 + dl];
      unsigned short o3 = tile[(u*4+3)*66 + dl];
      *(ushort4*)(Vt + ((size_t)(e*NBB + d0 + dl)) * NBB + k0 + (u << 2)) =
          make_ushort4(o0, o1, o2, o3);
    }
  } else {
    const int b2 = blockIdx.x - 2048;                 // [0,4096)
    const int n  = b2*8 + (threadIdx.x >> 5);         // row [0,32768)
    const int col = (threadIdx.x & 31) * 8;           // 8 elems of 256
    const size_t off = (size_t)n * DDIM + 256 + col;
    f32x4 a0 = *(const f32x4*)(qkv + off),   a1 = *(const f32x4*)(qkv + off + 4);
    f32x4 n0 = *(const f32x4*)(noise + off), n1 = *(const f32x4*)(noise + off + 4);
    short8 o;
    o[0]=f2bf(a0[0]+n0[0]); o[1]=f2bf(a0[1]+n0[1]); o[2]=f2bf(a0[2]+n0[2]); o[3]=f2bf(a0[3]+n0[3]);
    o[4]=f2bf(a1[0]+n1[0]); o[5]=f2bf(a1[1]+n1[1]); o[6]=f2bf(a1[2]+n1[2]); o[7]=f2bf(a1[3]+n1[3]);
    *(short8*)(Kb + (size_t)n * 256 + col) = o;
  }
}

// ---------- kernel 2: fused attention ----------
// Block = (e, q-quarter): 4 waves x 16 q-rows each. 16x16x32 bf16 MFMA, swapped
// QK^T (S^T = mfma(K,Q)) -> lane-local softmax + in-register P via permlane.
// LDS 68KB: buf0/buf1 (2x32KB K/V tiles, read-XOR-swizzled), aud 2KB, pos 2KB.
__launch_bounds__(256, 2)
__global__ void k_attn(const float* __restrict__ qkv, const float* __restrict__ sp,
                       const unsigned char* __restrict__ m8, const int* __restrict__ m32,
                       const float* __restrict__ pos,
                       const unsigned short* __restrict__ Vt,
                       const unsigned short* __restrict__ Kb,
                       float* __restrict__ out){
  extern __shared__ unsigned char smem[];
  unsigned short* buf0 = (unsigned short*)smem;             // 64 x 256 bf16
  unsigned short* buf1 = (unsigned short*)(smem + 32768);   // 64 x 256 bf16
  unsigned*       audL = (unsigned*)(smem + 65536);         // 64 rows x 8 words
  float*          posx = (float*)(smem + 67584);            // 256
  float*          posy = (float*)(smem + 68608);            // 256

  // bid = x + 8*qq + 32*c ; e = 16x + c  -> the 4 q-quarters of an ensemble all
  // land on XCD x (bid%8) and launch within 24 bids of each other -> L2 reuse.
  const int bid = blockIdx.x;
  const int e   = ((bid & 7) << 4) + (bid >> 5);
  const int qq  = (bid >> 3) & 3;
  const int tid  = threadIdx.x;
  const int wave = tid >> 6;
  const int lane = tid & 63;
  const int g    = lane >> 4;
  const int u    = lane & 15;
  const int q0   = qq * 64 + wave * 16;        // first q-row of this wave
  const size_t ebase = (size_t)e * NBB;

  // ---- phase 0: positions; K0 prefetch flies under the aud compute ----
  {
    const float2 p = *(const float2*)(pos + (ebase + tid) * 2);
    posx[tid] = p.x; posy[tid] = p.y;
  }
  const unsigned probe = ((const unsigned*)m32)[tid & 63];
  const int isInt = !__any(probe > 1u);        // wave-uniform dtype probe
  __syncthreads();                             // pos ready

  gstage(Kb + ebase * 256, buf0, wave, lane);  // K tile 0 -> buf0 (in flight)

  // ---- phase 0b: audible bits. High-MLP form (16 indep int4 loads), with
  // j-staggered block order so the posx[k] reads are bank-conflict-free:
  // bank = (4*((ii+j)&7)+jj)%32 -> 8 distinct banks across the 8 j's; the 8
  // rows sharing a j read the SAME address (broadcast, free). Same math/bits.
  #pragma unroll
  for(int h = 0; h < 2; ++h){
    const int w   = tid + h * 256;             // word index within block [0,512)
    const int row = w >> 3;                    // q-row within block [0,64)
    const int j   = w & 7;                     // which 32-key word
    const float qx = posx[qq*64 + row], qy = posy[qq*64 + row];
    const size_t mbase = (ebase + qq*64 + row) * NBB + j * 32;
    unsigned wd = 0u;
    if(isInt){
      #pragma unroll
      for(int ii = 0; ii < 8; ++ii){
        const int blk = (ii + j) & 7;          // stagger by word index
        const int4 mv = *(const int4*)(m32 + mbase + blk * 4);
        const int mvals[4] = {mv.x, mv.y, mv.z, mv.w};
        #pragma unroll
        for(int jj = 0; jj < 4; ++jj){
          const int kk = blk * 4 + jj;
          const int k  = j * 32 + kk;
          const float dx = posx[k] - qx, dy = posy[k] - qy;
          // block fp-contract so sqrt boundary matches numpy exactly
          const float d2 = __fadd_rn(__fmul_rn(dx, dx), __fmul_rn(dy, dy));
          if((mvals[jj] != 0) && (sqrtf(d2) < 15.0f)) wd |= 1u << kk;
        }
      }
    } else {
      #pragma unroll
      for(int i = 0; i < 2; ++i){
        const int4 mv = *(const int4*)(m8 + mbase + i * 16);   // 16 bool bytes
        const int mvals[4] = {mv.x, mv.y, mv.z, mv.w};
        #pragma unroll
        for(int jt = 0; jt < 4; ++jt){
          const int jj = (jt + j) & 3;         // stagger byte-groups -> 2-way (free)
          #pragma unroll
          for(int b = 0; b < 4; ++b){
            const int kk = i * 16 + jj * 4 + b;
            const int k  = j * 32 + kk;
            const float dx = posx[k] - qx, dy = posy[k] - qy;
            const float d2 = __fadd_rn(__fmul_rn(dx, dx), __fmul_rn(dy, dy));
            if((((unsigned)mvals[jj] >> (8 * b)) & 0xFFu) && (sqrtf(d2) < 15.0f)) wd |= 1u << kk;
          }
        }
      }
    }
    audL[w] = wd;
  }

  // ---- phase 1: Q fragments from f32 global (scale + RNE cvt) ----
  const float scale = fabsf(sp[0]) + 1.0f;
  short8 qf[8];
  {
    const float* qrow = qkv + (ebase + q0 + u) * DDIM;
    #pragma unroll
    for(int dk = 0; dk < 8; ++dk){
      f32x4 a = *(const f32x4*)(qrow + dk*32 + g*8);
      f32x4 b = *(const f32x4*)(qrow + dk*32 + g*8 + 4);
      short8 f;
      f[0]=cvt1(a[0]*scale); f[1]=cvt1(a[1]*scale); f[2]=cvt1(a[2]*scale); f[3]=cvt1(a[3]*scale);
      f[4]=cvt1(b[0]*scale); f[5]=cvt1(b[1]*scale); f[6]=cvt1(b[2]*scale); f[7]=cvt1(b[3]*scale);
      qf[dk] = f;
    }
  }

  const f32x4 zero4 = {0.f, 0.f, 0.f, 0.f};
  f32x4 acc[16];
  #pragma unroll
  for(int nt = 0; nt < 16; ++nt) acc[nt] = zero4;

  __syncthreads();                             // drains K0 gloads + audL visible

  // ---- phase 2: S^T = K Q^T, double-buffered pipeline (prefetch before MFMA) ----
  // acc[nt] at lane (g,u): S[k = nt*16 + g*4 + r][q = u]
  #pragma unroll
  for(int kq = 0; kq < 4; ++kq){
    unsigned short* cur = (kq & 1) ? buf1 : buf0;
    unsigned short* nxt = (kq & 1) ? buf0 : buf1;
    if(kq < 3) gstage(Kb + (ebase + (size_t)(kq+1) * 64) * 256, nxt, wave, lane);
    else       gstage(Vt + ebase * 256, nxt, wave, lane);   // V0 under softmax
    #pragma unroll
    for(int nth = 0; nth < 4; ++nth){
      const unsigned short* kr = cur + (nth*16 + u) * 256;
      const int sw = (u & 7) << 3;
      #pragma unroll
      for(int dk = 0; dk < 8; ++dk){
        short8 kb = *(const short8*)(kr + ((dk*32 + g*8) ^ sw));
        acc[kq*4 + nth] = __builtin_amdgcn_mfma_f32_16x16x32_bf16(kb, qf[dk], acc[kq*4 + nth], 0, 0, 0);
      }
    }
    if(kq < 3) __syncthreads();                // nxt tile staged; all waves past cur
  }

  // ---- phase 3: mask + softmax, lane-local rows + 2 shfl reduces ----
  unsigned wmask[8];
  {
    const unsigned* arow = audL + (wave*16 + u) * 8;   // own wave's rows
    #pragma unroll
    for(int j = 0; j < 8; ++j) wmask[j] = arow[j];
  }
  const unsigned anyw = wmask[0]|wmask[1]|wmask[2]|wmask[3]|wmask[4]|wmask[5]|wmask[6]|wmask[7];
  const unsigned long long rowsAny = __ballot(anyw != 0u);   // bit u = row u has keys

  float m0=-3.0e38f, m1=-3.0e38f, m2=-3.0e38f, m3=-3.0e38f;
  #pragma unroll
  for(int nt = 0; nt < 16; ++nt){
    const unsigned wv = wmask[nt >> 1] >> (((nt & 1) << 4) + g*4);
    f32x4 s = acc[nt];
    s[0] = s[0]*0.0625f + ((wv      & 1u) ? 0.0f : NEGV);  // /sqrt(256) + mask bias
    s[1] = s[1]*0.0625f + (((wv>>1) & 1u) ? 0.0f : NEGV);
    s[2] = s[2]*0.0625f + (((wv>>2) & 1u) ? 0.0f : NEGV);
    s[3] = s[3]*0.0625f + (((wv>>3) & 1u) ? 0.0f : NEGV);
    acc[nt] = s;
    m0 = fmaxf(m0, s[0]); m1 = fmaxf(m1, s[1]);
    m2 = fmaxf(m2, s[2]); m3 = fmaxf(m3, s[3]);
  }
  float mx = fmaxf(fmaxf(m0, m1), fmaxf(m2, m3));
  mx = fmaxf(mx, __shfl_xor(mx, 16));
  mx = fmaxf(mx, __shfl_xor(mx, 32));
  float s0=0.f, s1=0.f, s2=0.f, s3=0.f;
  #pragma unroll
  for(int nt = 0; nt < 16; ++nt){
    f32x4 p = acc[nt];
    p[0] = __expf(p[0] - mx); p[1] = __expf(p[1] - mx);
    p[2] = __expf(p[2] - mx); p[3] = __expf(p[3] - mx);
    acc[nt] = p;
    s0 += p[0]; s1 += p[1]; s2 += p[2]; s3 += p[3];
  }
  float ssum = (s0 + s1) + (s2 + s3);
  ssum += __shfl_xor(ssum, 16);
  ssum += __shfl_xor(ssum, 32);
  const float inv = 1.0f / ssum;               // ssum >= 1 always (max element)

  // ---- phase 3b: P -> bf16 in-register + permlane relayout to PV A-frags ----
  short8 pa[8];
  #pragma unroll
  for(int kt = 0; kt < 8; ++kt){
    unsigned cE = pk2(acc[2*kt][0]*inv,   acc[2*kt][1]*inv);
    unsigned dE = pk2(acc[2*kt][2]*inv,   acc[2*kt][3]*inv);
    unsigned cO = pk2(acc[2*kt+1][0]*inv, acc[2*kt+1][1]*inv);
    unsigned dO = pk2(acc[2*kt+1][2]*inv, acc[2*kt+1][3]*inv);
    swap32(cE, cO); swap16(cE, cO);
    swap32(dE, dO); swap16(dE, dO);
    union { short8 s; unsigned w[4]; } pk;
    pk.w[0] = cE; pk.w[1] = dE; pk.w[2] = cO; pk.w[3] = dO;
    pa[kt] = pk.s;
  }

  __syncthreads();                             // drains V0 gloads; all waves past QKT

  // ---- phase 4: x = P V, same double-buffered pipeline over Vt quarters ----
  #pragma unroll
  for(int dqt = 0; dqt < 4; ++dqt){
    unsigned short* cur = (dqt & 1) ? buf1 : buf0;
    unsigned short* nxt = (dqt & 1) ? buf0 : buf1;
    if(dqt < 3) gstage(Vt + (ebase + (size_t)(dqt+1) * 64) * 256, nxt, wave, lane);
    f32x4 xacc[4];
    #pragma unroll
    for(int dt = 0; dt < 4; ++dt) xacc[dt] = zero4;
    #pragma unroll
    for(int dt = 0; dt < 4; ++dt){
      const unsigned short* vr = cur + (dt*16 + u) * 256;
      const int sw = (u & 7) << 3;
      #pragma unroll
      for(int kt = 0; kt < 8; ++kt){
        short8 bv = *(const short8*)(vr + ((kt*32 + g*8) ^ sw));
        xacc[dt] = __builtin_amdgcn_mfma_f32_16x16x32_bf16(pa[kt], bv, xacc[dt], 0, 0, 0);
      }
    }
    #pragma unroll
    for(int r = 0; r < 4; ++r){
      const float zf = ((rowsAny >> (g*4 + r)) & 1ull) ? 1.0f : 0.0f;
      float* orow = out + (ebase + q0 + g*4 + r) * 256 + dqt*64;
      #pragma unroll
      for(int dt = 0; dt < 4; ++dt)
        orow[dt*16 + u] = xacc[dt][r] * zf;    // rows with no audible key -> 0
    }
    if(dqt < 3) __syncthreads();
  }
}

extern "C" void kernel_launch(void* const* d_in, const int* in_sizes, int n_in,
                              void* d_out, int out_size, void* d_ws, size_t ws_size,
                              hipStream_t stream){
  (void)in_sizes; (void)n_in; (void)out_size; (void)ws_size;  // needs 32 MB ws
  const float* qkv   = (const float*)d_in[0];
  const void*  mask  = d_in[1];
  const float* pos   = (const float*)d_in[2];
  const float* noise = (const float*)d_in[3];
  const float* sp    = (const float*)d_in[4];

  unsigned short* Vt = (unsigned short*)d_ws;
  unsigned short* Kb = (unsigned short*)((unsigned char*)d_ws + 16777216);
  float* outp = (float*)d_out;

  k_prep<<<6144, 256, 0, stream>>>(qkv, noise, Vt, Kb);

  hipFuncSetAttribute((const void*)k_attn, hipFuncAttributeMaxDynamicSharedMemorySize, 69632);
  k_attn<<<512, 256, 69632, stream>>>(qkv, sp,
                                      (const unsigned char*)mask, (const int*)mask,
                                      pos, Vt, Kb, outp);
}